// Round 9
// baseline (238.940 us; speedup 1.0000x reference)
//
#include <hip/hip_runtime.h>

// ---------- problem constants ----------
#define BB   4096   // batch
#define IN_  256
#define NN   128
#define KK   4
#define JJ   64
#define NG   512        // N*K
#define WS_  131072     // IN*NG
#define PER  131584     // WS_+NG
#define TP   263168     // 2*PER
#define OUTD 128

typedef __attribute__((ext_vector_type(8))) short short8;
typedef __attribute__((ext_vector_type(4))) float f32x4;

#define VW(N) asm volatile("s_waitcnt vmcnt(" #N ")" ::: "memory")

__device__ __forceinline__ unsigned short f2bf(float f){
  unsigned u = __float_as_uint(f);
  return (unsigned short)((u + 0x7fffu + ((u >> 16) & 1u)) >> 16);
}

__device__ __forceinline__ void gload16(const void* g, void* l){
  __builtin_amdgcn_global_load_lds((const __attribute__((address_space(1))) void*)g,
                                   (__attribute__((address_space(3))) void*)l, 16, 0, 0);
}

// sum over each 16-lane row via DPP (VALU pipe; replaces 4x ds_swizzle shfl)
__device__ __forceinline__ float rowred16(float s){
  s += __int_as_float(__builtin_amdgcn_update_dpp(0, __float_as_int(s), 0xB1,  0xF, 0xF, true)); // quad_perm xor1
  s += __int_as_float(__builtin_amdgcn_update_dpp(0, __float_as_int(s), 0x4E,  0xF, 0xF, true)); // quad_perm xor2
  s += __int_as_float(__builtin_amdgcn_update_dpp(0, __float_as_int(s), 0x124, 0xF, 0xF, true)); // row_ror:4
  s += __int_as_float(__builtin_amdgcn_update_dpp(0, __float_as_int(s), 0x128, 0xF, 0xF, true)); // row_ror:8
  return s;
}

// ---------- 1. f32 -> bf16 convert: x, Wb0, Wb1 ----------
#define XE  (4096u*256u)            // 1048576
#define W0E (XE + 8388608u)         // + 128*4*64*256
#define W1E (W0E + 4194304u)        // + 128*4*64*128

__global__ void k_convert(const float* __restrict__ x,
                          const float* __restrict__ w0,
                          const float* __restrict__ w1,
                          unsigned short* __restrict__ xb,
                          unsigned short* __restrict__ w0b,
                          unsigned short* __restrict__ w1b){
  size_t i = ((size_t)blockIdx.x*256 + threadIdx.x)*4;
  if (i >= W1E) return;
  const float* s; unsigned short* d; size_t off;
  if (i < XE)       { s = x;  d = xb;  off = i; }
  else if (i < W0E) { s = w0; d = w0b; off = i - XE; }
  else              { s = w1; d = w1b; off = i - W0E; }
  float4 v = *(const float4*)(s + off);
  ushort4 o;
  o.x = f2bf(v.x); o.y = f2bf(v.y); o.z = f2bf(v.z); o.w = f2bf(v.w);
  *(ushort4*)(d + off) = o;
}

// ---------- 2. hypernet MLP (context -> hv2[64]) ----------
__global__ void k_hyper(const float* __restrict__ ctx,
                        const float* __restrict__ h1w, const float* __restrict__ h1b,
                        const float* __restrict__ h2w, const float* __restrict__ h2b,
                        float* __restrict__ hv2){
  __shared__ float s1[32];
  int t = threadIdx.x;
  if (t < 32){
    float a = h1b[t];
    #pragma unroll 8
    for (int i = 0; i < 64; ++i) a += ctx[i]*h1w[t*64+i];
    s1[t] = fmaxf(a, 0.f);
  }
  __syncthreads();
  float a = h2b[t];
  #pragma unroll 8
  for (int i = 0; i < 32; ++i) a += s1[i]*h2w[t*32+i];
  hv2[t] = fmaxf(a, 0.f);
}

// ---------- 3. gw = hv2 @ h3w.T + h3b  ->  Wg_bf (1024x256 bf16), bg (1024 f32) ----------
__global__ void k_gw(const float* __restrict__ hv2,
                     const float* __restrict__ h3w, const float* __restrict__ h3b,
                     unsigned short* __restrict__ Wg_bf, float* __restrict__ bg){
  int t = threadIdx.x;
  int r = blockIdx.x*64 + (t >> 2);
  int q = t & 3;
  const float4* row = (const float4*)(h3w + (size_t)r*64);
  float a = 0.f;
  #pragma unroll
  for (int i = 0; i < 4; ++i){
    float4 v = row[q*4 + i];
    float4 h = *(const float4*)(hv2 + q*16 + i*4);
    a += v.x*h.x + v.y*h.y + v.z*h.z + v.w*h.w;
  }
  a += __shfl_xor(a, 1);
  a += __shfl_xor(a, 2);
  if (q == 0){
    a += h3b[r];
    if (r < WS_)          Wg_bf[r] = f2bf(a);
    else if (r < PER)     bg[r - WS_] = a;
    else if (r < PER+WS_) Wg_bf[WS_ + (r - PER)] = f2bf(a);
    else                  bg[512 + (r - (PER+WS_))] = a;
  }
}

// ---------- 4. gates GEMM: G_T[m(1024)][b(4096)] = sigmoid(Wg[m]·x[b] + bg[m]) ----------
__global__ __launch_bounds__(512, 1)
void k_gates(const unsigned short* __restrict__ Wg_bf,  // 1024 x 256
             const unsigned short* __restrict__ x_bf,   // 4096 x 256
             const float* __restrict__ bg,              // 1024
             float* __restrict__ GT){                    // 1024 x 4096
  __shared__ __align__(16) unsigned short As[128*64];
  __shared__ __align__(16) unsigned short Bs[256*64];
  const int tid  = threadIdx.x;
  const int lane = tid & 63;
  const int wid  = tid >> 6;
  const int wm = wid >> 2, wn = wid & 3;
  const int lrow = lane & 15, lk = lane >> 4;
  const int m0 = blockIdx.x*128;
  const int b0 = blockIdx.y*256;

  f32x4 zero = {0.f,0.f,0.f,0.f};
  f32x4 acc[4][4];
  #pragma unroll
  for (int i=0;i<4;++i)
    #pragma unroll
    for (int j=0;j<4;++j) acc[i][j] = zero;

  for (int kt = 0; kt < 256/64; ++kt){
    __syncthreads();
    #pragma unroll
    for (int i = 0; i < 2; ++i){
      int c = tid + i*512;
      int row = c >> 3, k8 = c & 7;
      uint4 v = *(const uint4*)(Wg_bf + (size_t)(m0+row)*256 + kt*64 + k8*8);
      int idx = (row*64 + k8*8) ^ ((row & 7) << 3);
      *(uint4*)(&As[idx]) = v;
    }
    #pragma unroll
    for (int i = 0; i < 4; ++i){
      int c = tid + i*512;
      int row = c >> 3, k8 = c & 7;
      uint4 v = *(const uint4*)(x_bf + (size_t)(b0+row)*256 + kt*64 + k8*8);
      int idx = (row*64 + k8*8) ^ ((row & 7) << 3);
      *(uint4*)(&Bs[idx]) = v;
    }
    __syncthreads();
    #pragma unroll
    for (int kk = 0; kk < 2; ++kk){
      short8 a[4], b[4];
      #pragma unroll
      for (int fm = 0; fm < 4; ++fm){
        int m = wm*64 + fm*16 + lrow;
        int idx = (m*64 + kk*32 + lk*8) ^ ((m & 7) << 3);
        a[fm] = *(const short8*)(&As[idx]);
      }
      #pragma unroll
      for (int fn = 0; fn < 4; ++fn){
        int r = wn*64 + fn*16 + lrow;
        int idx = (r*64 + kk*32 + lk*8) ^ ((r & 7) << 3);
        b[fn] = *(const short8*)(&Bs[idx]);
      }
      #pragma unroll
      for (int fm = 0; fm < 4; ++fm)
        #pragma unroll
        for (int fn = 0; fn < 4; ++fn)
          acc[fm][fn] = __builtin_amdgcn_mfma_f32_16x16x32_bf16(a[fm], b[fn], acc[fm][fn], 0, 0, 0);
    }
  }
  #pragma unroll
  for (int fm = 0; fm < 4; ++fm){
    float4 bgv = *(const float4*)(bg + m0 + wm*64 + fm*16 + lk*4);
    float bga[4] = {bgv.x, bgv.y, bgv.z, bgv.w};
    #pragma unroll
    for (int reg = 0; reg < 4; ++reg){
      int m = m0 + wm*64 + fm*16 + lk*4 + reg;
      #pragma unroll
      for (int fn = 0; fn < 4; ++fn){
        int b = b0 + wn*64 + fn*16 + lrow;
        float z = acc[fm][fn][reg] + bga[reg];
        GT[(size_t)m*4096 + b] = 1.f/(1.f + __expf(-z));
      }
    }
  }
}

// ---------- 5/6. fused DANN layer (Wb in registers, K=128 phases, DPP epi) ----------
// Per-wave Wb fragments are block constants -> loaded once global->VGPR
// (L0: 32 short8 = 128 regs, L1: 16). LDS holds ONLY the streaming A-tile,
// double-buffered at K=128 per phase:
//   L0: grid (n,khalf), BTR=256, 16 bt x 2 K-halves = 32 phases.
//   L1: grid (n,bhalf), BTR=128, 16 bt x 1      = 16 phases.
// Phase: [VW, barrier, STAGE(ph+1), {epi: gates}, 64 MFMA, {epi: DPP-reduce +
// 4 f32x4 stores}]. Exact drains: stage(ph)'s younger ops = G4+E4 iff prev
// phase was epi -> kt==0&&ph>0: VW(8); else VW(0).
// Epilogue reduce = DPP (quad_perm xor1/2 + row_ror 4/8), no ds_swizzle.
template<int KIN, int LAYER>
__global__ __launch_bounds__(512, 1)
void k_layer(const unsigned short* __restrict__ Abf,  // (4096, KIN) bf16
             const unsigned short* __restrict__ Wbf,  // (32768, KIN) bf16
             const float* __restrict__ bb,            // 32768
             const float* __restrict__ Ws,            // 128*256
             const float* __restrict__ GT,            // 1024 x 4096
             float* __restrict__ partg){              // [4][128][4096] f32
  constexpr int BTR   = (LAYER==0) ? 256 : 128;  // A-tile rows per phase
  constexpr int WN    = (LAYER==0) ? 2 : 4;      // waves across cols
  constexpr int KSL   = KIN/32;                  // b-frag k-slots: 8 / 4
  constexpr int PPB   = KIN/128;                 // phases per bt: 2 / 1
  constexpr int NBT   = 16;
  constexpr int NPH   = NBT*PPB;                 // 32 / 16
  constexpr int ABUF  = BTR*128;                 // shorts per A buffer
  __shared__ __align__(16) unsigned short lds[2*ABUF];

  const int tid  = threadIdx.x;
  const int lane = tid & 63;
  const int wid  = tid >> 6;
  const int wn   = wid % WN, wm = wid / WN;
  const int lrow = lane & 15, lk = lane >> 4;

  const int id      = blockIdx.x;                // 0..255
  const int n       = id >> 1;
  const int sub     = id & 1;                    // khalf (L0) / bhalf (L1)
  const int kgrp    = (LAYER==0) ? sub*2 + wn : wn;
  const int abase   = (LAYER==0) ? 0 : sub*2048;
  const int colbase = n*256 + ((LAYER==0) ? sub*128 : 0);

  f32x4 zero = {0.f,0.f,0.f,0.f};
  f32x4 acc[4][4];
  #pragma unroll
  for (int i=0;i<4;++i)
    #pragma unroll
    for (int jj=0;jj<4;++jj) acc[i][jj] = zero;

  // ---- prologue 1: per-wave Wb fragments, global -> registers ----
  short8 breg[KSL][4];
  {
    const unsigned short* wrow = Wbf + (size_t)(colbase + wn*64 + lrow)*KIN + lk*8;
    #pragma unroll
    for (int ks = 0; ks < KSL; ++ks)
      #pragma unroll
      for (int fn = 0; fn < 4; ++fn)
        breg[ks][fn] = *(const short8*)(wrow + (size_t)fn*16*KIN + ks*32);
  }

  // ---- A-tile stage: BTR x 128 as two 64-wide subtiles, swizzled src ----
  auto STAGE_A = [&](int buf, int bt, int kt){
    #pragma unroll
    for (int ktl = 0; ktl < 2; ++ktl)
      #pragma unroll
      for (int ii = 0; ii < BTR/64; ++ii){
        int c = ii*512 + tid;
        int r = c >> 3, kc = c & 7;
        const unsigned short* s = Abf + (size_t)(abase + bt*BTR + r)*KIN
                                  + kt*128 + ktl*64 + ((kc ^ (r&7))<<3);
        gload16(s, &lds[buf*ABUF + ktl*BTR*64 + (ii*512 + wid*64)*8]);
      }
  };

  STAGE_A(0, 0, 0);
  asm volatile("" ::: "memory");

  // block-constant epilogue params
  float bbv[4], wsv[4];
  #pragma unroll
  for (int fn = 0; fn < 4; ++fn){
    int cloc = ((LAYER==0) ? sub*128 : 0) + wn*64 + fn*16 + lrow;
    bbv[fn] = bb[n*256 + cloc];
    wsv[fn] = Ws[n*256 + cloc];
  }
  const float* gtrow = GT + (size_t)(LAYER*512 + n*4 + kgrp)*4096 + abase;
  float* prow = partg + (size_t)kgrp*524288 + (size_t)n*4096 + abase;

  int abuf = 0;
  #pragma unroll 1
  for (int bt = 0; bt < NBT; ++bt){
    #pragma unroll
    for (int kt = 0; kt < PPB; ++kt){
      const int  ph  = bt*PPB + kt;
      const bool epi = (kt == PPB-1);

      if (ph == 0)      VW(0);      // prologue (breg + A0) drained
      else if (kt == 0) VW(8);      // prev phase was epi: G4+E4 younger
      else              VW(0);      // nothing younger than stage(ph)
      __builtin_amdgcn_s_barrier();

      if (ph + 1 < NPH){
        int bt2 = bt, kt2 = kt + 1;
        if (kt2 == PPB){ kt2 = 0; bt2 = bt + 1; }
        STAGE_A(abuf ^ 1, bt2, kt2);
      }
      asm volatile("" ::: "memory");

      float4 gv[4];
      if (epi){
        #pragma unroll
        for (int fm = 0; fm < 4; ++fm)
          gv[fm] = *(const float4*)(gtrow + bt*BTR + wm*64 + fm*16 + lk*4);
        asm volatile("" ::: "memory");
      }

      // 64 MFMA: A from lds[abuf], B from registers
      #pragma unroll
      for (int kk = 0; kk < 4; ++kk){
        short8 a[4];
        #pragma unroll
        for (int fm = 0; fm < 4; ++fm){
          int m = wm*64 + fm*16 + lrow;
          int idx = abuf*ABUF + (kk>>1)*BTR*64
                    + ((m*64 + (kk&1)*32 + lk*8) ^ ((m & 7) << 3));
          a[fm] = *(const short8*)(&lds[idx]);
        }
        #pragma unroll
        for (int fm = 0; fm < 4; ++fm)
          #pragma unroll
          for (int fn = 0; fn < 4; ++fn)
            acc[fm][fn] = __builtin_amdgcn_mfma_f32_16x16x32_bf16(
                a[fm], breg[kt*4 + kk][fn], acc[fm][fn], 0, 0, 0);
      }

      if (epi){
        #pragma unroll
        for (int fm = 0; fm < 4; ++fm){
          float gr[4] = {gv[fm].x, gv[fm].y, gv[fm].z, gv[fm].w};
          float sums[4];
          #pragma unroll
          for (int reg = 0; reg < 4; ++reg){
            float s = 0.f;
            #pragma unroll
            for (int fn = 0; fn < 4; ++fn)
              s += fmaxf(acc[fm][fn][reg] + bbv[fn], 0.f) * wsv[fn];
            sums[reg] = rowred16(s * gr[reg]);
          }
          if (lrow == 0){
            float4 o; o.x = sums[0]; o.y = sums[1]; o.z = sums[2]; o.w = sums[3];
            *(float4*)(prow + bt*BTR + wm*64 + fm*16 + lk*4) = o;
          }
        }
        #pragma unroll
        for (int i2 = 0; i2 < 4; ++i2)
          #pragma unroll
          for (int j2 = 0; j2 < 4; ++j2) acc[i2][j2] = zero;
      }
      abuf ^= 1;
    }
  }
}

// ---------- 6.5 partial fold: out[b][n] = sum_wn partg[wn][n][b] + bs[n] ----------
template<int OUT_BF>
__global__ void k_mid(const float* __restrict__ partg, const float* __restrict__ bsv,
                      unsigned short* __restrict__ obf, float* __restrict__ of32){
  const int n = blockIdx.x;          // 128
  const int t = threadIdx.x;         // 256 threads x 16 b each
  const float* p = partg + (size_t)n*4096 + t*16;
  const float bsn = bsv[n];
  #pragma unroll
  for (int i = 0; i < 4; ++i){
    float4 s0 = *(const float4*)(p + i*4);
    float4 s1 = *(const float4*)(p + 524288 + i*4);
    float4 s2 = *(const float4*)(p + 2*524288 + i*4);
    float4 s3 = *(const float4*)(p + 3*524288 + i*4);
    float v0 = ((s0.x + s1.x) + s2.x) + s3.x + bsn;
    float v1 = ((s0.y + s1.y) + s2.y) + s3.y + bsn;
    float v2 = ((s0.z + s1.z) + s2.z) + s3.z + bsn;
    float v3 = ((s0.w + s1.w) + s2.w) + s3.w + bsn;
    size_t b = (size_t)t*16 + i*4;
    if (OUT_BF){
      obf[(b+0)*128 + n] = f2bf(v0);
      obf[(b+1)*128 + n] = f2bf(v1);
      obf[(b+2)*128 + n] = f2bf(v2);
      obf[(b+3)*128 + n] = f2bf(v3);
    } else {
      of32[(b+0)*128 + n] = v0;
      of32[(b+1)*128 + n] = v1;
      of32[(b+2)*128 + n] = v2;
      of32[(b+3)*128 + n] = v3;
    }
  }
}

// ---------- 7. final projection: out = cur1 @ Wout.T + bout ----------
__global__ void k_final(const float* __restrict__ out1, const float* __restrict__ Wout,
                        const float* __restrict__ bout, float* __restrict__ out){
  int t = blockIdx.x*256 + threadIdx.x;
  int b = t >> 7, o = t & 127;
  const float4* cr = (const float4*)(out1 + (size_t)b*128);
  const float4* wr = (const float4*)(Wout + (size_t)o*128);
  float a = 0.f;
  #pragma unroll
  for (int i = 0; i < 32; ++i){
    float4 c = cr[i], w = wr[i];
    a += c.x*w.x + c.y*w.y + c.z*w.z + c.w*w.w;
  }
  out[t] = a + bout[o];
}

// ---------- launch ----------
extern "C" void kernel_launch(void* const* d_in, const int* in_sizes, int n_in,
                              void* d_out, int out_size, void* d_ws, size_t ws_size,
                              hipStream_t stream){
  const float* x    = (const float*)d_in[0];
  const float* ctx  = (const float*)d_in[1];
  const float* Wb0  = (const float*)d_in[2];
  const float* bb0  = (const float*)d_in[3];
  const float* Ws0  = (const float*)d_in[4];
  const float* bs0  = (const float*)d_in[5];
  const float* Wb1  = (const float*)d_in[6];
  const float* bb1  = (const float*)d_in[7];
  const float* Ws1  = (const float*)d_in[8];
  const float* bs1  = (const float*)d_in[9];
  const float* Wout = (const float*)d_in[10];
  const float* bout = (const float*)d_in[11];
  const float* h1w  = (const float*)d_in[12];
  const float* h1b  = (const float*)d_in[13];
  const float* h2w  = (const float*)d_in[14];
  const float* h2b  = (const float*)d_in[15];
  const float* h3w  = (const float*)d_in[16];
  const float* h3b  = (const float*)d_in[17];
  float* out = (float*)d_out;

  char* ws = (char*)d_ws;
  size_t o = 0;
  unsigned short* x_bf  = (unsigned short*)(ws + o); o += (size_t)4096*256*2;
  unsigned short* W0b   = (unsigned short*)(ws + o); o += (size_t)8388608*2;
  unsigned short* W1b   = (unsigned short*)(ws + o); o += (size_t)4194304*2;
  unsigned short* Wg_bf = (unsigned short*)(ws + o); o += (size_t)1024*256*2;
  float* bg   = (float*)(ws + o); o += 1024*4;
  float* hv2  = (float*)(ws + o); o += 256;
  float* GT   = (float*)(ws + o); o += (size_t)1024*4096*4;
  unsigned short* cur_bf = (unsigned short*)(ws + o); o += (size_t)4096*128*2;
  float* out1 = (float*)(ws + o); o += (size_t)4096*128*4;
  float* partg0 = (float*)(ws + o); o += (size_t)4*128*4096*4;   // 8 MB
  float* partg1 = (float*)W0b;      // alias: W0b dead after k_layer0

  k_convert<<<13312, 256, 0, stream>>>(x, Wb0, Wb1, x_bf, W0b, W1b);
  k_hyper<<<1, 64, 0, stream>>>(ctx, h1w, h1b, h2w, h2b, hv2);
  k_gw<<<4112, 256, 0, stream>>>(hv2, h3w, h3b, Wg_bf, bg);
  k_gates<<<dim3(8, 16), 512, 0, stream>>>(Wg_bf, x_bf, bg, GT);
  k_layer<256, 0><<<256, 512, 0, stream>>>(x_bf, W0b, bb0, Ws0, GT, partg0);
  k_mid<1><<<128, 256, 0, stream>>>(partg0, bs0, cur_bf, nullptr);
  k_layer<128, 1><<<256, 512, 0, stream>>>(cur_bf, W1b, bb1, Ws1, GT, partg1);
  k_mid<0><<<128, 256, 0, stream>>>(partg1, bs1, nullptr, out1);
  k_final<<<2048, 256, 0, stream>>>(out1, Wout, bout, out);
}

// Round 10
// 214.097 us; speedup vs baseline: 1.1160x; 1.1160x over previous
//
#include <hip/hip_runtime.h>

// ---------- problem constants ----------
#define BB   4096
#define IN_  256
#define NN   128
#define NG   512
#define WS_  131072     // IN*NG
#define PER  131584     // WS_+NG
#define TP   263168     // 2*PER

typedef __attribute__((ext_vector_type(8))) short short8;
typedef __attribute__((ext_vector_type(4))) float f32x4;

#define VW(N) asm volatile("s_waitcnt vmcnt(" #N ")" ::: "memory")

__device__ __forceinline__ unsigned short f2bf(float f){
  unsigned u = __float_as_uint(f);
  return (unsigned short)((u + 0x7fffu + ((u >> 16) & 1u)) >> 16);
}

__device__ __forceinline__ void gload16(const void* g, void* l){
  __builtin_amdgcn_global_load_lds((const __attribute__((address_space(1))) void*)g,
                                   (__attribute__((address_space(3))) void*)l, 16, 0, 0);
}

// sum over each 16-lane row via DPP (VALU pipe; validated in R9)
__device__ __forceinline__ float rowred16(float s){
  s += __int_as_float(__builtin_amdgcn_update_dpp(0, __float_as_int(s), 0xB1,  0xF, 0xF, true)); // quad_perm xor1
  s += __int_as_float(__builtin_amdgcn_update_dpp(0, __float_as_int(s), 0x4E,  0xF, 0xF, true)); // quad_perm xor2
  s += __int_as_float(__builtin_amdgcn_update_dpp(0, __float_as_int(s), 0x124, 0xF, 0xF, true)); // row_ror:4
  s += __int_as_float(__builtin_amdgcn_update_dpp(0, __float_as_int(s), 0x128, 0xF, 0xF, true)); // row_ror:8
  return s;
}

// ---------- 1. f32 -> bf16 convert: x only ----------
__global__ void k_convert(const float* __restrict__ x, unsigned short* __restrict__ xb){
  size_t i = ((size_t)blockIdx.x*256 + threadIdx.x)*4;
  float4 v = *(const float4*)(x + i);
  ushort4 o;
  o.x = f2bf(v.x); o.y = f2bf(v.y); o.z = f2bf(v.z); o.w = f2bf(v.w);
  *(ushort4*)(xb + i) = o;
}

// ---------- 2. hypernet MLP + gw matvec (merged) ----------
// Every block recomputes the tiny MLP (ctx->hv2[64], ~6 KFLOP), then computes
// 64 rows of gw = hv2 @ h3w.T + h3b with 8 lanes/row (coalesced 128B/row).
__global__ __launch_bounds__(512)
void k_gw(const float* __restrict__ ctx,
          const float* __restrict__ h1w, const float* __restrict__ h1b,
          const float* __restrict__ h2w, const float* __restrict__ h2b,
          const float* __restrict__ h3w, const float* __restrict__ h3b,
          unsigned short* __restrict__ Wg_bf, float* __restrict__ bg){
  __shared__ float s1[32];
  __shared__ float hv2[64];
  const int t = threadIdx.x;
  if (t < 32){
    float a = h1b[t];
    #pragma unroll 8
    for (int i = 0; i < 64; ++i) a += ctx[i]*h1w[t*64+i];
    s1[t] = fmaxf(a, 0.f);
  }
  __syncthreads();
  if (t < 64){
    float a = h2b[t];
    #pragma unroll 8
    for (int i = 0; i < 32; ++i) a += s1[i]*h2w[t*32+i];
    hv2[t] = fmaxf(a, 0.f);
  }
  __syncthreads();

  const int r = blockIdx.x*64 + (t >> 3);
  const int q = t & 7;
  const float4* row = (const float4*)(h3w + (size_t)r*64);
  float4 v0 = row[q*2], v1 = row[q*2+1];
  float4 h0 = *(const float4*)(hv2 + q*8), h1 = *(const float4*)(hv2 + q*8 + 4);
  float a = v0.x*h0.x + v0.y*h0.y + v0.z*h0.z + v0.w*h0.w
          + v1.x*h1.x + v1.y*h1.y + v1.z*h1.z + v1.w*h1.w;
  a += __shfl_xor(a, 1);
  a += __shfl_xor(a, 2);
  a += __shfl_xor(a, 4);
  if (q == 0){
    a += h3b[r];
    if (r < WS_)          Wg_bf[r] = f2bf(a);
    else if (r < PER)     bg[r - WS_] = a;
    else if (r < PER+WS_) Wg_bf[WS_ + (r - PER)] = f2bf(a);
    else                  bg[512 + (r - (PER+WS_))] = a;
  }
}

// ---------- 4. gates GEMM: G_T[m][b] = sigmoid(Wg[m]·x[b] + bg[m]) ----------
__global__ __launch_bounds__(512, 1)
void k_gates(const unsigned short* __restrict__ Wg_bf,
             const unsigned short* __restrict__ x_bf,
             const float* __restrict__ bg,
             float* __restrict__ GT){
  __shared__ __align__(16) unsigned short As[128*64];
  __shared__ __align__(16) unsigned short Bs[256*64];
  const int tid  = threadIdx.x;
  const int lane = tid & 63;
  const int wid  = tid >> 6;
  const int wm = wid >> 2, wn = wid & 3;
  const int lrow = lane & 15, lk = lane >> 4;
  const int m0 = blockIdx.x*128;
  const int b0 = blockIdx.y*256;

  f32x4 zero = {0.f,0.f,0.f,0.f};
  f32x4 acc[4][4];
  #pragma unroll
  for (int i=0;i<4;++i)
    #pragma unroll
    for (int j=0;j<4;++j) acc[i][j] = zero;

  for (int kt = 0; kt < 256/64; ++kt){
    __syncthreads();
    #pragma unroll
    for (int i = 0; i < 2; ++i){
      int c = tid + i*512;
      int row = c >> 3, k8 = c & 7;
      uint4 v = *(const uint4*)(Wg_bf + (size_t)(m0+row)*256 + kt*64 + k8*8);
      int idx = (row*64 + k8*8) ^ ((row & 7) << 3);
      *(uint4*)(&As[idx]) = v;
    }
    #pragma unroll
    for (int i = 0; i < 4; ++i){
      int c = tid + i*512;
      int row = c >> 3, k8 = c & 7;
      uint4 v = *(const uint4*)(x_bf + (size_t)(b0+row)*256 + kt*64 + k8*8);
      int idx = (row*64 + k8*8) ^ ((row & 7) << 3);
      *(uint4*)(&Bs[idx]) = v;
    }
    __syncthreads();
    #pragma unroll
    for (int kk = 0; kk < 2; ++kk){
      short8 a[4], b[4];
      #pragma unroll
      for (int fm = 0; fm < 4; ++fm){
        int m = wm*64 + fm*16 + lrow;
        int idx = (m*64 + kk*32 + lk*8) ^ ((m & 7) << 3);
        a[fm] = *(const short8*)(&As[idx]);
      }
      #pragma unroll
      for (int fn = 0; fn < 4; ++fn){
        int r = wn*64 + fn*16 + lrow;
        int idx = (r*64 + kk*32 + lk*8) ^ ((r & 7) << 3);
        b[fn] = *(const short8*)(&Bs[idx]);
      }
      #pragma unroll
      for (int fm = 0; fm < 4; ++fm)
        #pragma unroll
        for (int fn = 0; fn < 4; ++fn)
          acc[fm][fn] = __builtin_amdgcn_mfma_f32_16x16x32_bf16(a[fm], b[fn], acc[fm][fn], 0, 0, 0);
    }
  }
  #pragma unroll
  for (int fm = 0; fm < 4; ++fm){
    float4 bgv = *(const float4*)(bg + m0 + wm*64 + fm*16 + lk*4);
    float bga[4] = {bgv.x, bgv.y, bgv.z, bgv.w};
    #pragma unroll
    for (int reg = 0; reg < 4; ++reg){
      int m = m0 + wm*64 + fm*16 + lk*4 + reg;
      #pragma unroll
      for (int fn = 0; fn < 4; ++fn){
        int b = b0 + wn*64 + fn*16 + lrow;
        float z = acc[fm][fn][reg] + bga[reg];
        GT[(size_t)m*4096 + b] = 1.f/(1.f + __expf(-z));
      }
    }
  }
}

// ---------- 5/6. fused DANN layer (R8 structure + hoisted offsets + DPP epi
//               + Wb staged directly from f32) ----------
// L0: block=(n,khalf): Wb 128x256 resident (64KB); A stream BTR=256, NT=4.
// L1: block=(n,bhalf): Wb 256x128 resident (64KB); A stream BTR=128, NT=2.
// Phase: [VW, barrier, STAGE_A(ph+1), {kt0: gates}, MFMA, {epi: DPP-reduce
// + 4 f32x4 stores}]. Drains (exact, order-pinned): ph0->VW(0);
// kt<=1 -> VW(4) (G4 or E4 younger); else VW(0).
// All ds_read addresses = precomputed lane offsets, kk folded via ^64B,
// abuf via ^ABYTES (bit-disjoint; shift distributes over XOR).
template<int KIN, int LAYER>
__global__ __launch_bounds__(512, 1)
void k_layer(const unsigned short* __restrict__ Abf,  // (4096, KIN) bf16
             const float* __restrict__ Wf32,          // (32768, KIN) f32
             const float* __restrict__ bb,
             const float* __restrict__ Ws,
             const float* __restrict__ GT,            // 1024 x 4096
             float* __restrict__ partg){              // [4][128][4096] f32
  constexpr int NT     = KIN/64;                 // 4 / 2
  constexpr int SC     = (LAYER==0) ? 128 : 256;
  constexpr int WN     = (LAYER==0) ? 2 : 4;
  constexpr int BTR    = (LAYER==0) ? 256 : 128;
  constexpr int NBT    = 16;
  constexpr int AI     = BTR/64;                 // A-stage instrs/wave
  constexpr int ABUFS  = BTR*64;                 // shorts per A buffer
  constexpr unsigned ABYTES = ABUFS*2;           // 32768 / 16384
  constexpr int WBOFFS = 2*ABUFS;                // shorts
  constexpr unsigned WBYTES = WBOFFS*2;
  constexpr unsigned KTB = SC*64*2;              // bytes per Wb kt-tile
  __shared__ __align__(16) unsigned short lds[WBOFFS + SC*64*NT];

  const int tid  = threadIdx.x;
  const int lane = tid & 63;
  const int wid  = tid >> 6;
  const int wn   = wid % WN, wm = wid / WN;
  const int lrow = lane & 15, lk = lane >> 4;

  const int id      = blockIdx.x;                // 0..255
  const int n       = id >> 1;
  const int sub     = id & 1;
  const int kgrp    = (LAYER==0) ? sub*2 + wn : wn;
  const int abase   = (LAYER==0) ? 0 : sub*2048;
  const int colbase = n*256 + ((LAYER==0) ? sub*128 : 0);

  f32x4 zero = {0.f,0.f,0.f,0.f};
  f32x4 acc[4][4];
  #pragma unroll
  for (int i=0;i<4;++i)
    #pragma unroll
    for (int jj=0;jj<4;++jj) acc[i][jj] = zero;

  auto STAGE_A = [&](int buf, int bt, int kt){
    #pragma unroll
    for (int i = 0; i < AI; ++i){
      int c = i*512 + tid;
      int r = c >> 3, kc = c & 7;
      const unsigned short* s = Abf + (size_t)(abase + bt*BTR + r)*KIN + kt*64 + ((kc ^ (r&7))<<3);
      gload16(s, &lds[buf*ABUFS + (i*512 + wid*64)*8]);
    }
  };

  // prologue: A phase-0 (async to LDS), then Wb f32 -> bf16 swizzled staging
  STAGE_A(0, 0, 0);
  asm volatile("" ::: "memory");
  {
    constexpr int CHPR = KIN/8;                  // 16B chunks per Wb row
    #pragma unroll
    for (int half = 0; half < 2; ++half){
      float4 va[4], vb[4];
      #pragma unroll
      for (int j = 0; j < 4; ++j){
        int c = (half*4 + j)*512 + tid;          // 4096 chunks total
        int r = c / CHPR, q = c % CHPR;
        const float4* s = (const float4*)(Wf32 + (size_t)(colbase + r)*KIN + q*8);
        va[j] = s[0]; vb[j] = s[1];
      }
      #pragma unroll
      for (int j = 0; j < 4; ++j){
        int c = (half*4 + j)*512 + tid;
        int r = c / CHPR, q = c % CHPR;
        int kt = q >> 3, k8 = q & 7;
        short8 p;
        p[0] = (short)f2bf(va[j].x); p[1] = (short)f2bf(va[j].y);
        p[2] = (short)f2bf(va[j].z); p[3] = (short)f2bf(va[j].w);
        p[4] = (short)f2bf(vb[j].x); p[5] = (short)f2bf(vb[j].y);
        p[6] = (short)f2bf(vb[j].z); p[7] = (short)f2bf(vb[j].w);
        int dst = WBOFFS + kt*SC*64 + ((r*64 + k8*8) ^ ((r&7)<<3));
        *(short8*)(&lds[dst]) = p;
      }
    }
  }
  asm volatile("s_waitcnt lgkmcnt(0)" ::: "memory");

  // block-constant epilogue params
  float bbv[4], wsv[4];
  #pragma unroll
  for (int fn = 0; fn < 4; ++fn){
    int cloc = ((LAYER==0) ? sub*128 : 0) + wn*64 + fn*16 + lrow;
    bbv[fn] = bb[n*256 + cloc];
    wsv[fn] = Ws[n*256 + cloc];
  }
  const float* gtrow = GT + (size_t)(LAYER*512 + n*4 + kgrp)*4096 + abase;
  float* prow = partg + (size_t)kgrp*524288 + (size_t)n*4096 + abase;

  // precomputed lane-local LDS byte offsets (loop-invariant)
  unsigned aoff[4], boff[4];
  #pragma unroll
  for (int fm = 0; fm < 4; ++fm){
    int m = wm*64 + fm*16 + lrow;
    aoff[fm] = 2u*((unsigned)((m*64 + lk*8) ^ ((m & 7) << 3)));
  }
  #pragma unroll
  for (int fn = 0; fn < 4; ++fn){
    int r = wn*64 + fn*16 + lrow;
    boff[fn] = 2u*((unsigned)((r*64 + lk*8) ^ ((r & 7) << 3)));
  }
  const char* ldsc = (const char*)lds;
  unsigned abufB = 0;

  #pragma unroll 1
  for (int bt = 0; bt < NBT; ++bt){
    float4 gv[4];
    #pragma unroll
    for (int kt = 0; kt < NT; ++kt){
      const int  ph  = bt*NT + kt;
      const bool epi = (kt == NT-1);

      if (ph == 0)      VW(0);
      else if (kt <= 1) VW(4);
      else              VW(0);
      __builtin_amdgcn_s_barrier();

      if (ph + 1 < NBT*NT){
        int bt2 = bt, kt2 = kt + 1;
        if (kt2 == NT){ kt2 = 0; bt2 = bt + 1; }
        STAGE_A(abufB ? 0 : 1, bt2, kt2);
      }
      asm volatile("" ::: "memory");

      if (kt == 0){
        #pragma unroll
        for (int fm = 0; fm < 4; ++fm)
          gv[fm] = *(const float4*)(gtrow + bt*BTR + wm*64 + fm*16 + lk*4);
        asm volatile("" ::: "memory");
      }

      #pragma unroll
      for (int kk = 0; kk < 2; ++kk){
        short8 a[4], b[4];
        #pragma unroll
        for (int fm = 0; fm < 4; ++fm)
          a[fm] = *(const short8*)(ldsc + (abufB + (aoff[fm] ^ (unsigned)(kk*64))));
        #pragma unroll
        for (int fn = 0; fn < 4; ++fn)
          b[fn] = *(const short8*)(ldsc + WBYTES + kt*KTB + (boff[fn] ^ (unsigned)(kk*64)));
        #pragma unroll
        for (int fm = 0; fm < 4; ++fm)
          #pragma unroll
          for (int fn = 0; fn < 4; ++fn)
            acc[fm][fn] = __builtin_amdgcn_mfma_f32_16x16x32_bf16(a[fm], b[fn], acc[fm][fn], 0, 0, 0);
      }

      if (epi){
        #pragma unroll
        for (int fm = 0; fm < 4; ++fm){
          float gr[4] = {gv[fm].x, gv[fm].y, gv[fm].z, gv[fm].w};
          float sums[4];
          #pragma unroll
          for (int reg = 0; reg < 4; ++reg){
            float s = 0.f;
            #pragma unroll
            for (int fn = 0; fn < 4; ++fn)
              s += fmaxf(acc[fm][fn][reg] + bbv[fn], 0.f) * wsv[fn];
            sums[reg] = rowred16(s * gr[reg]);
          }
          if (lrow == 0){
            float4 o; o.x = sums[0]; o.y = sums[1]; o.z = sums[2]; o.w = sums[3];
            *(float4*)(prow + bt*BTR + wm*64 + fm*16 + lk*4) = o;
          }
        }
        #pragma unroll
        for (int i2 = 0; i2 < 4; ++i2)
          #pragma unroll
          for (int j2 = 0; j2 < 4; ++j2) acc[i2][j2] = zero;
      }
      abufB ^= ABYTES;
    }
  }
}

// ---------- 6.5 partial fold: out[b][n] = sum_k partg[k][n][b] + bs[n] ----------
template<int OUT_BF>
__global__ void k_mid(const float* __restrict__ partg, const float* __restrict__ bsv,
                      unsigned short* __restrict__ obf, float* __restrict__ of32){
  const int n = blockIdx.x;
  const int t = threadIdx.x;
  const float* p = partg + (size_t)n*4096 + t*16;
  const float bsn = bsv[n];
  #pragma unroll
  for (int i = 0; i < 4; ++i){
    float4 s0 = *(const float4*)(p + i*4);
    float4 s1 = *(const float4*)(p + 524288 + i*4);
    float4 s2 = *(const float4*)(p + 2*524288 + i*4);
    float4 s3 = *(const float4*)(p + 3*524288 + i*4);
    float v0 = ((s0.x + s1.x) + s2.x) + s3.x + bsn;
    float v1 = ((s0.y + s1.y) + s2.y) + s3.y + bsn;
    float v2 = ((s0.z + s1.z) + s2.z) + s3.z + bsn;
    float v3 = ((s0.w + s1.w) + s2.w) + s3.w + bsn;
    size_t b = (size_t)t*16 + i*4;
    if (OUT_BF){
      obf[(b+0)*128 + n] = f2bf(v0);
      obf[(b+1)*128 + n] = f2bf(v1);
      obf[(b+2)*128 + n] = f2bf(v2);
      obf[(b+3)*128 + n] = f2bf(v3);
    } else {
      of32[(b+0)*128 + n] = v0;
      of32[(b+1)*128 + n] = v1;
      of32[(b+2)*128 + n] = v2;
      of32[(b+3)*128 + n] = v3;
    }
  }
}

// ---------- 7. final projection: out = cur1 @ Wout.T + bout ----------
__global__ void k_final(const float* __restrict__ out1, const float* __restrict__ Wout,
                        const float* __restrict__ bout, float* __restrict__ out){
  int t = blockIdx.x*256 + threadIdx.x;
  int b = t >> 7, o = t & 127;
  const float4* cr = (const float4*)(out1 + (size_t)b*128);
  const float4* wr = (const float4*)(Wout + (size_t)o*128);
  float a = 0.f;
  #pragma unroll
  for (int i = 0; i < 32; ++i){
    float4 c = cr[i], w = wr[i];
    a += c.x*w.x + c.y*w.y + c.z*w.z + c.w*w.w;
  }
  out[t] = a + bout[o];
}

// ---------- launch ----------
extern "C" void kernel_launch(void* const* d_in, const int* in_sizes, int n_in,
                              void* d_out, int out_size, void* d_ws, size_t ws_size,
                              hipStream_t stream){
  const float* x    = (const float*)d_in[0];
  const float* ctx  = (const float*)d_in[1];
  const float* Wb0  = (const float*)d_in[2];
  const float* bb0  = (const float*)d_in[3];
  const float* Ws0  = (const float*)d_in[4];
  const float* bs0  = (const float*)d_in[5];
  const float* Wb1  = (const float*)d_in[6];
  const float* bb1  = (const float*)d_in[7];
  const float* Ws1  = (const float*)d_in[8];
  const float* bs1  = (const float*)d_in[9];
  const float* Wout = (const float*)d_in[10];
  const float* bout = (const float*)d_in[11];
  const float* h1w  = (const float*)d_in[12];
  const float* h1b  = (const float*)d_in[13];
  const float* h2w  = (const float*)d_in[14];
  const float* h2b  = (const float*)d_in[15];
  const float* h3w  = (const float*)d_in[16];
  const float* h3b  = (const float*)d_in[17];
  float* out = (float*)d_out;

  char* ws = (char*)d_ws;
  size_t o = 0;
  unsigned short* x_bf  = (unsigned short*)(ws + o); o += (size_t)4096*256*2;
  unsigned short* Wg_bf = (unsigned short*)(ws + o); o += (size_t)1024*256*2;
  float* bg     = (float*)(ws + o); o += 1024*4;
  float* GT     = (float*)(ws + o); o += (size_t)1024*4096*4;
  unsigned short* cur_bf = (unsigned short*)(ws + o); o += (size_t)4096*128*2;
  float* out1   = (float*)(ws + o); o += (size_t)4096*128*4;
  float* partg0 = (float*)(ws + o); o += (size_t)4*128*4096*4;   // 8 MB
  float* partg1 = (float*)(ws + o); o += (size_t)4*128*4096*4;   // 8 MB

  k_convert<<<1024, 256, 0, stream>>>(x, x_bf);
  k_gw<<<4112, 512, 0, stream>>>(ctx, h1w, h1b, h2w, h2b, h3w, h3b, Wg_bf, bg);
  k_gates<<<dim3(8, 16), 512, 0, stream>>>(Wg_bf, x_bf, bg, GT);
  k_layer<256, 0><<<256, 512, 0, stream>>>(x_bf, Wb0, bb0, Ws0, GT, partg0);
  k_mid<1><<<128, 256, 0, stream>>>(partg0, bs0, cur_bf, nullptr);
  k_layer<128, 1><<<256, 512, 0, stream>>>(cur_bf, Wb1, bb1, Ws1, GT, partg1);
  k_mid<0><<<128, 256, 0, stream>>>(partg1, bs1, nullptr, out1);
  k_final<<<2048, 256, 0, stream>>>(out1, Wout, bout, out);
}

// Round 11
// 211.721 us; speedup vs baseline: 1.1286x; 1.0112x over previous
//
#include <hip/hip_runtime.h>

// ---------- problem constants ----------
#define BB   4096
#define IN_  256
#define NN   128
#define NG   512
#define WS_  131072     // IN*NG
#define PER  131584     // WS_+NG
#define TP   263168     // 2*PER

typedef __attribute__((ext_vector_type(8))) short short8;
typedef __attribute__((ext_vector_type(4))) float f32x4;

#define VW(N) asm volatile("s_waitcnt vmcnt(" #N ")" ::: "memory")

__device__ __forceinline__ unsigned short f2bf(float f){
  unsigned u = __float_as_uint(f);
  return (unsigned short)((u + 0x7fffu + ((u >> 16) & 1u)) >> 16);
}

__device__ __forceinline__ void gload16(const void* g, void* l){
  __builtin_amdgcn_global_load_lds((const __attribute__((address_space(1))) void*)g,
                                   (__attribute__((address_space(3))) void*)l, 16, 0, 0);
}

// sum over each 16-lane row via DPP (VALU pipe)
__device__ __forceinline__ float rowred16(float s){
  s += __int_as_float(__builtin_amdgcn_update_dpp(0, __float_as_int(s), 0xB1,  0xF, 0xF, true));
  s += __int_as_float(__builtin_amdgcn_update_dpp(0, __float_as_int(s), 0x4E,  0xF, 0xF, true));
  s += __int_as_float(__builtin_amdgcn_update_dpp(0, __float_as_int(s), 0x124, 0xF, 0xF, true));
  s += __int_as_float(__builtin_amdgcn_update_dpp(0, __float_as_int(s), 0x128, 0xF, 0xF, true));
  return s;
}

// ---------- 1. f32 -> bf16 convert: x only ----------
__global__ void k_convert(const float* __restrict__ x, unsigned short* __restrict__ xb){
  size_t i = ((size_t)blockIdx.x*256 + threadIdx.x)*4;
  float4 v = *(const float4*)(x + i);
  ushort4 o;
  o.x = f2bf(v.x); o.y = f2bf(v.y); o.z = f2bf(v.z); o.w = f2bf(v.w);
  *(ushort4*)(xb + i) = o;
}

// ---------- 2. hypernet MLP + gw matvec (merged) ----------
__global__ __launch_bounds__(512)
void k_gw(const float* __restrict__ ctx,
          const float* __restrict__ h1w, const float* __restrict__ h1b,
          const float* __restrict__ h2w, const float* __restrict__ h2b,
          const float* __restrict__ h3w, const float* __restrict__ h3b,
          unsigned short* __restrict__ Wg_bf, float* __restrict__ bg){
  __shared__ float s1[32];
  __shared__ float hv2[64];
  const int t = threadIdx.x;
  if (t < 32){
    float a = h1b[t];
    #pragma unroll 8
    for (int i = 0; i < 64; ++i) a += ctx[i]*h1w[t*64+i];
    s1[t] = fmaxf(a, 0.f);
  }
  __syncthreads();
  if (t < 64){
    float a = h2b[t];
    #pragma unroll 8
    for (int i = 0; i < 32; ++i) a += s1[i]*h2w[t*32+i];
    hv2[t] = fmaxf(a, 0.f);
  }
  __syncthreads();

  const int r = blockIdx.x*64 + (t >> 3);
  const int q = t & 7;
  const float4* row = (const float4*)(h3w + (size_t)r*64);
  float4 v0 = row[q*2], v1 = row[q*2+1];
  float4 h0 = *(const float4*)(hv2 + q*8), h1 = *(const float4*)(hv2 + q*8 + 4);
  float a = v0.x*h0.x + v0.y*h0.y + v0.z*h0.z + v0.w*h0.w
          + v1.x*h1.x + v1.y*h1.y + v1.z*h1.z + v1.w*h1.w;
  a += __shfl_xor(a, 1);
  a += __shfl_xor(a, 2);
  a += __shfl_xor(a, 4);
  if (q == 0){
    a += h3b[r];
    if (r < WS_)          Wg_bf[r] = f2bf(a);
    else if (r < PER)     bg[r - WS_] = a;
    else if (r < PER+WS_) Wg_bf[WS_ + (r - PER)] = f2bf(a);
    else                  bg[512 + (r - (PER+WS_))] = a;
  }
}

// ---------- 4. gates GEMM: G_T[m][b] = sigmoid(Wg[m]·x[b] + bg[m]) ----------
__global__ __launch_bounds__(512, 1)
void k_gates(const unsigned short* __restrict__ Wg_bf,
             const unsigned short* __restrict__ x_bf,
             const float* __restrict__ bg,
             float* __restrict__ GT){
  __shared__ __align__(16) unsigned short As[128*64];
  __shared__ __align__(16) unsigned short Bs[256*64];
  const int tid  = threadIdx.x;
  const int lane = tid & 63;
  const int wid  = tid >> 6;
  const int wm = wid >> 2, wn = wid & 3;
  const int lrow = lane & 15, lk = lane >> 4;
  const int m0 = blockIdx.x*128;
  const int b0 = blockIdx.y*256;

  f32x4 zero = {0.f,0.f,0.f,0.f};
  f32x4 acc[4][4];
  #pragma unroll
  for (int i=0;i<4;++i)
    #pragma unroll
    for (int j=0;j<4;++j) acc[i][j] = zero;

  for (int kt = 0; kt < 256/64; ++kt){
    __syncthreads();
    #pragma unroll
    for (int i = 0; i < 2; ++i){
      int c = tid + i*512;
      int row = c >> 3, k8 = c & 7;
      uint4 v = *(const uint4*)(Wg_bf + (size_t)(m0+row)*256 + kt*64 + k8*8);
      int idx = (row*64 + k8*8) ^ ((row & 7) << 3);
      *(uint4*)(&As[idx]) = v;
    }
    #pragma unroll
    for (int i = 0; i < 4; ++i){
      int c = tid + i*512;
      int row = c >> 3, k8 = c & 7;
      uint4 v = *(const uint4*)(x_bf + (size_t)(b0+row)*256 + kt*64 + k8*8);
      int idx = (row*64 + k8*8) ^ ((row & 7) << 3);
      *(uint4*)(&Bs[idx]) = v;
    }
    __syncthreads();
    #pragma unroll
    for (int kk = 0; kk < 2; ++kk){
      short8 a[4], b[4];
      #pragma unroll
      for (int fm = 0; fm < 4; ++fm){
        int m = wm*64 + fm*16 + lrow;
        int idx = (m*64 + kk*32 + lk*8) ^ ((m & 7) << 3);
        a[fm] = *(const short8*)(&As[idx]);
      }
      #pragma unroll
      for (int fn = 0; fn < 4; ++fn){
        int r = wn*64 + fn*16 + lrow;
        int idx = (r*64 + kk*32 + lk*8) ^ ((r & 7) << 3);
        b[fn] = *(const short8*)(&Bs[idx]);
      }
      #pragma unroll
      for (int fm = 0; fm < 4; ++fm)
        #pragma unroll
        for (int fn = 0; fn < 4; ++fn)
          acc[fm][fn] = __builtin_amdgcn_mfma_f32_16x16x32_bf16(a[fm], b[fn], acc[fm][fn], 0, 0, 0);
    }
  }
  #pragma unroll
  for (int fm = 0; fm < 4; ++fm){
    float4 bgv = *(const float4*)(bg + m0 + wm*64 + fm*16 + lk*4);
    float bga[4] = {bgv.x, bgv.y, bgv.z, bgv.w};
    #pragma unroll
    for (int reg = 0; reg < 4; ++reg){
      int m = m0 + wm*64 + fm*16 + lk*4 + reg;
      #pragma unroll
      for (int fn = 0; fn < 4; ++fn){
        int b = b0 + wn*64 + fn*16 + lrow;
        float z = acc[fm][fn][reg] + bga[reg];
        GT[(size_t)m*4096 + b] = 1.f/(1.f + __expf(-z));
      }
    }
  }
}

// ---------- 5/6. fused DANN layer (16 waves = 4/SIMD; Wb-resident) ----------
// 1024-thread blocks: 16 waves tile (WM x WN) = L0 8x2 / L1 4x4; per-wave
// sub-tile 32 rows x 64 cols -> fm2, fn4, kk2 = 16 MFMA/phase/wave.
// LDS: A-dbuf (2xBTR*64 bf16) + resident Wb (SC x KIN bf16, staged from f32
// with inline cvt in prologue). Phase: [VW, barrier, STAGE_A(ph+1),
// {kt0: G2 gates}, MFMA, {epi: DPP-reduce + E2 stores}].
// Exact drains (per-wave): ph0 -> VW(0); NT=4: kt<=1 -> VW(2), else VW(0);
// NT=2: VW(2). (AI stage ops drained; G2/E2 are the only younger ops.)
template<int KIN, int LAYER>
__global__ __launch_bounds__(1024, 1)
void k_layer(const unsigned short* __restrict__ Abf,  // (4096, KIN) bf16
             const float* __restrict__ Wf32,          // (32768, KIN) f32
             const float* __restrict__ bb,
             const float* __restrict__ Ws,
             const float* __restrict__ GT,            // 1024 x 4096
             float* __restrict__ partg){              // [4][128][4096] f32
  constexpr int NT     = KIN/64;                 // 4 / 2
  constexpr int SC     = (LAYER==0) ? 128 : 256;
  constexpr int WN     = SC/64;                  // 2 / 4
  constexpr int BTR    = (LAYER==0) ? 256 : 128;
  constexpr int NBT    = 16;
  constexpr int NPH    = NBT*NT;
  constexpr int AI     = BTR/128;                // A-stage instrs/wave: 2 / 1
  constexpr int ABUFS  = BTR*64;                 // shorts per A buffer
  constexpr unsigned ABYTES = ABUFS*2;
  constexpr int WBOFFS = 2*ABUFS;                // shorts
  constexpr unsigned WBYTES = WBOFFS*2;
  constexpr unsigned KTB = SC*64*2;              // bytes per Wb kt-tile
  __shared__ __align__(16) unsigned short lds[WBOFFS + SC*64*NT];

  const int tid  = threadIdx.x;                  // 0..1023
  const int lane = tid & 63;
  const int wid  = tid >> 6;                     // 0..15
  const int wn   = wid % WN, wm = wid / WN;      // L0: wm 0..7; L1: wm 0..3
  const int lrow = lane & 15, lk = lane >> 4;

  const int id      = blockIdx.x;                // 0..255
  const int n       = id >> 1;
  const int sub     = id & 1;
  const int kgrp    = (LAYER==0) ? sub*2 + wn : wn;
  const int abase   = (LAYER==0) ? 0 : sub*2048;
  const int colbase = n*256 + ((LAYER==0) ? sub*128 : 0);

  f32x4 zero = {0.f,0.f,0.f,0.f};
  f32x4 acc[2][4];
  #pragma unroll
  for (int i=0;i<2;++i)
    #pragma unroll
    for (int jj=0;jj<4;++jj) acc[i][jj] = zero;

  auto STAGE_A = [&](int buf, int bt, int kt){
    #pragma unroll
    for (int i = 0; i < AI; ++i){
      int c = i*1024 + tid;
      int r = c >> 3, kc = c & 7;
      const unsigned short* s = Abf + (size_t)(abase + bt*BTR + r)*KIN + kt*64 + ((kc ^ (r&7))<<3);
      gload16(s, &lds[buf*ABUFS + (i*1024 + wid*64)*8]);
    }
  };

  // prologue: A phase-0 (async), then Wb f32->bf16 swizzled staging (4096 chunks)
  STAGE_A(0, 0, 0);
  asm volatile("" ::: "memory");
  {
    constexpr int CHPR = KIN/8;                  // 16B-chunks per Wb row
    float4 va[4], vb[4];
    #pragma unroll
    for (int j = 0; j < 4; ++j){
      int c = j*1024 + tid;
      int r = c / CHPR, q = c % CHPR;
      const float4* s = (const float4*)(Wf32 + (size_t)(colbase + r)*KIN + q*8);
      va[j] = s[0]; vb[j] = s[1];
    }
    #pragma unroll
    for (int j = 0; j < 4; ++j){
      int c = j*1024 + tid;
      int r = c / CHPR, q = c % CHPR;
      int kt = q >> 3, k8 = q & 7;
      short8 p;
      p[0] = (short)f2bf(va[j].x); p[1] = (short)f2bf(va[j].y);
      p[2] = (short)f2bf(va[j].z); p[3] = (short)f2bf(va[j].w);
      p[4] = (short)f2bf(vb[j].x); p[5] = (short)f2bf(vb[j].y);
      p[6] = (short)f2bf(vb[j].z); p[7] = (short)f2bf(vb[j].w);
      int dst = WBOFFS + kt*SC*64 + ((r*64 + k8*8) ^ ((r&7)<<3));
      *(short8*)(&lds[dst]) = p;
    }
  }
  asm volatile("s_waitcnt lgkmcnt(0)" ::: "memory");

  // block-constant epilogue params
  float bbv[4], wsv[4];
  #pragma unroll
  for (int fn = 0; fn < 4; ++fn){
    int cloc = ((LAYER==0) ? sub*128 : 0) + wn*64 + fn*16 + lrow;
    bbv[fn] = bb[n*256 + cloc];
    wsv[fn] = Ws[n*256 + cloc];
  }
  const float* gtrow = GT + (size_t)(LAYER*512 + n*4 + kgrp)*4096 + abase;
  float* prow = partg + (size_t)kgrp*524288 + (size_t)n*4096 + abase;

  // precomputed lane-local LDS byte offsets (loop-invariant)
  unsigned aoff[2], boff[4];
  #pragma unroll
  for (int fm = 0; fm < 2; ++fm){
    int m = wm*32 + fm*16 + lrow;
    aoff[fm] = 2u*((unsigned)((m*64 + lk*8) ^ ((m & 7) << 3)));
  }
  #pragma unroll
  for (int fn = 0; fn < 4; ++fn){
    int r = wn*64 + fn*16 + lrow;
    boff[fn] = 2u*((unsigned)((r*64 + lk*8) ^ ((r & 7) << 3)));
  }
  const char* ldsc = (const char*)lds;
  unsigned abufB = 0;

  #pragma unroll 1
  for (int bt = 0; bt < NBT; ++bt){
    float4 gv[2];
    #pragma unroll
    for (int kt = 0; kt < NT; ++kt){
      const int  ph  = bt*NT + kt;
      const bool epi = (kt == NT-1);

      if (ph == 0)                VW(0);
      else if (NT == 2)           VW(2);
      else if (kt <= 1)           VW(2);
      else                        VW(0);
      __builtin_amdgcn_s_barrier();

      if (ph + 1 < NPH){
        int bt2 = bt, kt2 = kt + 1;
        if (kt2 == NT){ kt2 = 0; bt2 = bt + 1; }
        STAGE_A(abufB ? 0 : 1, bt2, kt2);
      }
      asm volatile("" ::: "memory");

      if (kt == 0){
        #pragma unroll
        for (int fm = 0; fm < 2; ++fm)
          gv[fm] = *(const float4*)(gtrow + bt*BTR + wm*32 + fm*16 + lk*4);
        asm volatile("" ::: "memory");
      }

      #pragma unroll
      for (int kk = 0; kk < 2; ++kk){
        short8 a[2], b[4];
        #pragma unroll
        for (int fm = 0; fm < 2; ++fm)
          a[fm] = *(const short8*)(ldsc + (abufB + (aoff[fm] ^ (unsigned)(kk*64))));
        #pragma unroll
        for (int fn = 0; fn < 4; ++fn)
          b[fn] = *(const short8*)(ldsc + WBYTES + kt*KTB + (boff[fn] ^ (unsigned)(kk*64)));
        #pragma unroll
        for (int fm = 0; fm < 2; ++fm)
          #pragma unroll
          for (int fn = 0; fn < 4; ++fn)
            acc[fm][fn] = __builtin_amdgcn_mfma_f32_16x16x32_bf16(a[fm], b[fn], acc[fm][fn], 0, 0, 0);
      }

      if (epi){
        #pragma unroll
        for (int fm = 0; fm < 2; ++fm){
          float gr[4] = {gv[fm].x, gv[fm].y, gv[fm].z, gv[fm].w};
          float sums[4];
          #pragma unroll
          for (int reg = 0; reg < 4; ++reg){
            float s = 0.f;
            #pragma unroll
            for (int fn = 0; fn < 4; ++fn)
              s += fmaxf(acc[fm][fn][reg] + bbv[fn], 0.f) * wsv[fn];
            sums[reg] = rowred16(s * gr[reg]);
          }
          if (lrow == 0){
            float4 o; o.x = sums[0]; o.y = sums[1]; o.z = sums[2]; o.w = sums[3];
            *(float4*)(prow + bt*BTR + wm*32 + fm*16 + lk*4) = o;
          }
        }
        #pragma unroll
        for (int i2 = 0; i2 < 2; ++i2)
          #pragma unroll
          for (int j2 = 0; j2 < 4; ++j2) acc[i2][j2] = zero;
      }
      abufB ^= ABYTES;
    }
  }
}

// ---------- 6.5 partial fold: out[b][n] = sum_k partg[k][n][b] + bs[n] ----------
template<int OUT_BF>
__global__ void k_mid(const float* __restrict__ partg, const float* __restrict__ bsv,
                      unsigned short* __restrict__ obf, float* __restrict__ of32){
  const int n = blockIdx.x;
  const int t = threadIdx.x;
  const float* p = partg + (size_t)n*4096 + t*16;
  const float bsn = bsv[n];
  #pragma unroll
  for (int i = 0; i < 4; ++i){
    float4 s0 = *(const float4*)(p + i*4);
    float4 s1 = *(const float4*)(p + 524288 + i*4);
    float4 s2 = *(const float4*)(p + 2*524288 + i*4);
    float4 s3 = *(const float4*)(p + 3*524288 + i*4);
    float v0 = ((s0.x + s1.x) + s2.x) + s3.x + bsn;
    float v1 = ((s0.y + s1.y) + s2.y) + s3.y + bsn;
    float v2 = ((s0.z + s1.z) + s2.z) + s3.z + bsn;
    float v3 = ((s0.w + s1.w) + s2.w) + s3.w + bsn;
    size_t b = (size_t)t*16 + i*4;
    if (OUT_BF){
      obf[(b+0)*128 + n] = f2bf(v0);
      obf[(b+1)*128 + n] = f2bf(v1);
      obf[(b+2)*128 + n] = f2bf(v2);
      obf[(b+3)*128 + n] = f2bf(v3);
    } else {
      of32[(b+0)*128 + n] = v0;
      of32[(b+1)*128 + n] = v1;
      of32[(b+2)*128 + n] = v2;
      of32[(b+3)*128 + n] = v3;
    }
  }
}

// ---------- 7. final projection: out = cur1 @ Wout.T + bout ----------
__global__ void k_final(const float* __restrict__ out1, const float* __restrict__ Wout,
                        const float* __restrict__ bout, float* __restrict__ out){
  int t = blockIdx.x*256 + threadIdx.x;
  int b = t >> 7, o = t & 127;
  const float4* cr = (const float4*)(out1 + (size_t)b*128);
  const float4* wr = (const float4*)(Wout + (size_t)o*128);
  float a = 0.f;
  #pragma unroll
  for (int i = 0; i < 32; ++i){
    float4 c = cr[i], w = wr[i];
    a += c.x*w.x + c.y*w.y + c.z*w.z + c.w*w.w;
  }
  out[t] = a + bout[o];
}

// ---------- launch ----------
extern "C" void kernel_launch(void* const* d_in, const int* in_sizes, int n_in,
                              void* d_out, int out_size, void* d_ws, size_t ws_size,
                              hipStream_t stream){
  const float* x    = (const float*)d_in[0];
  const float* ctx  = (const float*)d_in[1];
  const float* Wb0  = (const float*)d_in[2];
  const float* bb0  = (const float*)d_in[3];
  const float* Ws0  = (const float*)d_in[4];
  const float* bs0  = (const float*)d_in[5];
  const float* Wb1  = (const float*)d_in[6];
  const float* bb1  = (const float*)d_in[7];
  const float* Ws1  = (const float*)d_in[8];
  const float* bs1  = (const float*)d_in[9];
  const float* Wout = (const float*)d_in[10];
  const float* bout = (const float*)d_in[11];
  const float* h1w  = (const float*)d_in[12];
  const float* h1b  = (const float*)d_in[13];
  const float* h2w  = (const float*)d_in[14];
  const float* h2b  = (const float*)d_in[15];
  const float* h3w  = (const float*)d_in[16];
  const float* h3b  = (const float*)d_in[17];
  float* out = (float*)d_out;

  char* ws = (char*)d_ws;
  size_t o = 0;
  unsigned short* x_bf  = (unsigned short*)(ws + o); o += (size_t)4096*256*2;
  unsigned short* Wg_bf = (unsigned short*)(ws + o); o += (size_t)1024*256*2;
  float* bg     = (float*)(ws + o); o += 1024*4;
  float* GT     = (float*)(ws + o); o += (size_t)1024*4096*4;
  unsigned short* cur_bf = (unsigned short*)(ws + o); o += (size_t)4096*128*2;
  float* out1   = (float*)(ws + o); o += (size_t)4096*128*4;
  float* partg0 = (float*)(ws + o); o += (size_t)4*128*4096*4;   // 8 MB
  float* partg1 = (float*)(ws + o); o += (size_t)4*128*4096*4;   // 8 MB

  k_convert<<<1024, 256, 0, stream>>>(x, x_bf);
  k_gw<<<4112, 512, 0, stream>>>(ctx, h1w, h1b, h2w, h2b, h3w, h3b, Wg_bf, bg);
  k_gates<<<dim3(8, 16), 512, 0, stream>>>(Wg_bf, x_bf, bg, GT);
  k_layer<256, 0><<<256, 1024, 0, stream>>>(x_bf, Wb0, bb0, Ws0, GT, partg0);
  k_mid<1><<<128, 256, 0, stream>>>(partg0, bs0, cur_bf, nullptr);
  k_layer<128, 1><<<256, 1024, 0, stream>>>(cur_bf, Wb1, bb1, Ws1, GT, partg1);
  k_mid<0><<<128, 256, 0, stream>>>(partg1, bs1, nullptr, out1);
  k_final<<<2048, 256, 0, stream>>>(out1, Wout, bout, out);
}